// Round 1
// baseline (171.999 us; speedup 1.0000x reference)
//
#include <hip/hip_runtime.h>

#define IN_DIM 2048
#define OUT_DIM 2048
#define EPS 1e-8f

#define BM 256
#define BN 128
#define BK 64
#define NT (IN_DIM / BK)       // 32 K-tiles
#define SLOT 24576             // A 16K + B 8K per slot
#define LDS_SZ 73728           // 3 slots

using int32x4 = __attribute__((ext_vector_type(4))) int;

// ---------------- Kernel 1: sum of |W| ----------------
__global__ __launch_bounds__(256) void absum_kernel(const float* __restrict__ w,
                                                    double* __restrict__ sum, int n4) {
    int tid = blockIdx.x * blockDim.x + threadIdx.x;
    int stride = gridDim.x * blockDim.x;
    float s = 0.f;
    for (int i = tid; i < n4; i += stride) {
        float4 v = ((const float4*)w)[i];
        s += fabsf(v.x) + fabsf(v.y) + fabsf(v.z) + fabsf(v.w);
    }
    for (int off = 32; off; off >>= 1) s += __shfl_down(s, off);
    __shared__ float wsum[4];
    int lane = threadIdx.x & 63, wave = threadIdx.x >> 6;
    if (lane == 0) wsum[wave] = s;
    __syncthreads();
    if (threadIdx.x == 0) {
        double t = (double)wsum[0] + (double)wsum[1] + (double)wsum[2] + (double)wsum[3];
        atomicAdd(sum, t);
    }
}

// ---------------- Kernel 2: quantize W to ternary int8 ----------------
__global__ __launch_bounds__(256) void quantw_kernel(const float* __restrict__ w,
                                                     const double* __restrict__ sumptr,
                                                     signed char* __restrict__ wq,
                                                     float* __restrict__ alpha_out, int n4) {
    float alpha = fmaxf((float)(*sumptr * (1.0 / (double)(IN_DIM * OUT_DIM))), EPS);
    int i = blockIdx.x * blockDim.x + threadIdx.x;
    if (i == 0) *alpha_out = alpha;
    if (i >= n4) return;
    float4 v = ((const float4*)w)[i];
    char4 q;
    q.x = (signed char)fminf(fmaxf(rintf(v.x / alpha), -1.f), 1.f);
    q.y = (signed char)fminf(fmaxf(rintf(v.y / alpha), -1.f), 1.f);
    q.z = (signed char)fminf(fmaxf(rintf(v.z / alpha), -1.f), 1.f);
    q.w = (signed char)fminf(fmaxf(rintf(v.w / alpha), -1.f), 1.f);
    ((char4*)wq)[i] = q;
}

// ---------------- Kernel 3: per-token beta + quantize x ----------------
__global__ __launch_bounds__(256) void quantx_kernel(const float* __restrict__ x,
                                                     signed char* __restrict__ xq,
                                                     float* __restrict__ beta_arr,
                                                     int tokens) {
    const int tid = threadIdx.x;
    const int lane = tid & 63, wave = tid >> 6;
    __shared__ float wmax[4];
    for (int t = blockIdx.x; t < tokens; t += gridDim.x) {
        const float4* row = (const float4*)(x + (size_t)t * IN_DIM);
        float4 v0 = row[tid];
        float4 v1 = row[tid + 256];
        float m = fmaxf(fmaxf(fmaxf(fabsf(v0.x), fabsf(v0.y)), fmaxf(fabsf(v0.z), fabsf(v0.w))),
                        fmaxf(fmaxf(fabsf(v1.x), fabsf(v1.y)), fmaxf(fabsf(v1.z), fabsf(v1.w))));
        for (int off = 32; off; off >>= 1) m = fmaxf(m, __shfl_xor(m, off));
        if (lane == 0) wmax[wave] = m;
        __syncthreads();
        m = fmaxf(fmaxf(wmax[0], wmax[1]), fmaxf(wmax[2], wmax[3]));
        float beta = fmaxf(m * (1.f / 127.f), EPS);
        if (tid == 0) beta_arr[t] = beta;
        char4 q0, q1;
        q0.x = (signed char)fminf(fmaxf(rintf(v0.x / beta), -127.f), 127.f);
        q0.y = (signed char)fminf(fmaxf(rintf(v0.y / beta), -127.f), 127.f);
        q0.z = (signed char)fminf(fmaxf(rintf(v0.z / beta), -127.f), 127.f);
        q0.w = (signed char)fminf(fmaxf(rintf(v0.w / beta), -127.f), 127.f);
        q1.x = (signed char)fminf(fmaxf(rintf(v1.x / beta), -127.f), 127.f);
        q1.y = (signed char)fminf(fmaxf(rintf(v1.y / beta), -127.f), 127.f);
        q1.z = (signed char)fminf(fmaxf(rintf(v1.z / beta), -127.f), 127.f);
        q1.w = (signed char)fminf(fmaxf(rintf(v1.w / beta), -127.f), 127.f);
        char4* orow = (char4*)(xq + (size_t)t * IN_DIM);
        orow[tid] = q0;
        orow[tid + 256] = q1;
        __syncthreads();
    }
}

// ---------------- GEMM helper ----------------
__device__ __forceinline__ void gll(const signed char* g, signed char* l) {
    __builtin_amdgcn_global_load_lds((const __attribute__((address_space(1))) void*)g,
        (__attribute__((address_space(3))) void*)l, 16, 0, 0);
}

// ---------------- Kernel 4: int8 MFMA GEMM, 256x128 tile, 2 blocks/CU ----------------
// 256 threads = 4 waves (2M x 2N); wave-tile 128x64; acc[8][4] (128 VGPR).
// LDS: 3 rotating slots of 24 KiB (A 16K granule-major + B 8K granule-major) = 72 KiB
// -> 2 independent workgroups per CU (144 KiB LDS, 8 waves): while one block's waves
// sit in their ds_read burst / barrier, the other block feeds the MFMA pipe.
// Stage 2 tiles ahead; counted vmcnt(6) (never 0 in steady state); 1 barrier per K-tile.
// Granule-major map: addr = g*1024 + kg*256 + r*16  (row = 16g+r, k = 16*kg) -> 0 bank
// conflicts on ds_read_b128 and linear wave-uniform gll destinations (base + lane*16).
__global__ __launch_bounds__(256, 2) void gemm_kernel(const signed char* __restrict__ xq,
                                                      const signed char* __restrict__ wq,
                                                      const float* __restrict__ beta,
                                                      const float* __restrict__ alpha_p,
                                                      float* __restrict__ out) {
    extern __shared__ signed char lds[];   // 73728
    const int tid = threadIdx.x;
    const int lane = tid & 63;
    const int wave = tid >> 6;             // 0..3
    const int wm = wave >> 1;              // 0..1 (row half)
    const int wn = wave & 1;               // 0..1 (col half)
    const int col0 = blockIdx.x * BN;
    const int row0 = blockIdx.y * BM;

    // staging: thread t, chunk c writes LDS bytes [t*16 + c*4096, +16)
    // -> granule g = (t>>6)+4c, k-group kg = (t>>4)&3, r = t&15
    // -> source element (row = 16*((t>>6)+4c) + (t&15), k = 16*((t>>4)&3))
    const int f = tid * 16;
    const int srow = ((tid >> 6) << 4) + (tid & 15);
    const int skg = ((tid >> 4) & 3) << 4;
    const signed char* aP[4];
    const signed char* bP[2];
#pragma unroll
    for (int c = 0; c < 4; ++c) aP[c] = xq + (size_t)(row0 + srow + 64 * c) * IN_DIM + skg;
#pragma unroll
    for (int c = 0; c < 2; ++c) bP[c] = wq + (size_t)(col0 + srow + 64 * c) * IN_DIM + skg;

    const int kr = ((lane >> 4) << 8) + ((lane & 15) << 4);
    const int aoff = wm * 8192 + kr;           // + m*1024
    const int boff = 16384 + wn * 4096 + kr;   // + n*1024

    int32x4 acc[8][4] = {};

    // prologue: stage tiles 0,1 into slots 0,1 (6 glls each, A then B)
#pragma unroll
    for (int c = 0; c < 4; ++c) gll(aP[c], lds + f + c * 4096);
#pragma unroll
    for (int c = 0; c < 2; ++c) gll(bP[c], lds + 16384 + f + c * 4096);
#pragma unroll
    for (int c = 0; c < 4; ++c) gll(aP[c] + BK, lds + SLOT + f + c * 4096);
#pragma unroll
    for (int c = 0; c < 2; ++c) gll(bP[c] + BK, lds + SLOT + 16384 + f + c * 4096);
    asm volatile("s_waitcnt vmcnt(6)" ::: "memory");   // tile 0's 6 landed
    __builtin_amdgcn_s_barrier();

    int s = 0, d = 2;   // read slot = T%3, dest slot = (T+2)%3
    for (int T = 0; T < NT; ++T) {
        const signed char* ls = lds + s * SLOT;
        signed char* ldst = lds + d * SLOT;
        int32x4 af[8], bf[4];
#pragma unroll
        for (int m = 0; m < 4; ++m) af[m] = *(const int32x4*)(ls + aoff + m * 1024);
#pragma unroll
        for (int n = 0; n < 4; ++n) bf[n] = *(const int32x4*)(ls + boff + n * 1024);
        if (T < NT - 2) {   // stage tile T+2: A granules
            const size_t ko = (size_t)(T + 2) * BK;
#pragma unroll
            for (int c = 0; c < 4; ++c) gll(aP[c] + ko, ldst + f + c * 4096);
        }
#pragma unroll
        for (int m = 0; m < 4; ++m) af[4 + m] = *(const int32x4*)(ls + aoff + 4096 + m * 1024);
        __builtin_amdgcn_s_setprio(1);
#pragma unroll
        for (int m = 0; m < 4; ++m)
#pragma unroll
            for (int n = 0; n < 4; ++n)
                acc[m][n] = __builtin_amdgcn_mfma_i32_16x16x64_i8(af[m], bf[n], acc[m][n], 0, 0, 0);
        __builtin_amdgcn_s_setprio(0);
        if (T < NT - 2) {   // stage tile T+2: B granules
            const size_t ko = (size_t)(T + 2) * BK;
#pragma unroll
            for (int c = 0; c < 2; ++c) gll(bP[c] + ko, ldst + 16384 + f + c * 4096);
        }
        __builtin_amdgcn_s_setprio(1);
#pragma unroll
        for (int m = 0; m < 4; ++m)
#pragma unroll
            for (int n = 0; n < 4; ++n)
                acc[4 + m][n] = __builtin_amdgcn_mfma_i32_16x16x64_i8(af[4 + m], bf[n], acc[4 + m][n], 0, 0, 0);
        __builtin_amdgcn_s_setprio(0);
        if (T < NT - 1) {
            // outstanding: 6 for T+1 (older) + 6 for T+2 (newer, if staged).
            // Gate T+1's 6; never drain the newest in steady state.
            if (T < NT - 2) asm volatile("s_waitcnt vmcnt(6)" ::: "memory");
            else            asm volatile("s_waitcnt vmcnt(0)" ::: "memory");
            __builtin_amdgcn_s_barrier();
        }
        s = (s == 2) ? 0 : s + 1;
        d = (d == 2) ? 0 : d + 1;
    }

    // epilogue: dequant + store (C layout: col=lane&15, row=(lane>>4)*4+reg)
    const float alpha = *alpha_p;
#pragma unroll
    for (int mi = 0; mi < 8; ++mi) {
        int rbase = row0 + wm * 128 + mi * 16 + ((lane >> 4) << 2);
#pragma unroll
        for (int r = 0; r < 4; ++r) {
            int row = rbase + r;
            float scale = alpha * beta[row];
#pragma unroll
            for (int n = 0; n < 4; ++n) {
                int col = col0 + wn * 64 + n * 16 + (lane & 15);
                out[(size_t)row * OUT_DIM + col] = (float)acc[mi][n][r] * scale;
            }
        }
    }
}

extern "C" void kernel_launch(void* const* d_in, const int* in_sizes, int n_in,
                              void* d_out, int out_size, void* d_ws, size_t ws_size,
                              hipStream_t stream) {
    const float* x = (const float*)d_in[0];
    const float* w = (const float*)d_in[1];
    float* out = (float*)d_out;

    const int tokens = in_sizes[0] / IN_DIM;          // 16384
    const int n_w = in_sizes[1];                      // 4194304
    const int n_w4 = n_w / 4;

    char* ws = (char*)d_ws;
    double* d_sum = (double*)ws;                      // 8 B
    float* d_alpha = (float*)(ws + 8);                // 4 B
    float* d_beta = (float*)(ws + 256);               // tokens * 4 B
    signed char* d_wq = (signed char*)(ws + 256 + 65536);
    signed char* d_xq = d_wq + (size_t)n_w;

    hipMemsetAsync(d_ws, 0, 16, stream);

    absum_kernel<<<1024, 256, 0, stream>>>(w, d_sum, n_w4);
    quantw_kernel<<<(n_w4 + 255) / 256, 256, 0, stream>>>(w, d_sum, d_wq, d_alpha, n_w4);
    quantx_kernel<<<2048, 256, 0, stream>>>(x, d_xq, d_beta, tokens);

    hipFuncSetAttribute((const void*)gemm_kernel,
                        hipFuncAttributeMaxDynamicSharedMemorySize, LDS_SZ);

    dim3 grid(OUT_DIM / BN, tokens / BM);             // (16, 64)
    gemm_kernel<<<grid, 256, LDS_SZ, stream>>>(d_xq, d_wq, d_beta, d_alpha, out);
}

// Round 2
// 152.691 us; speedup vs baseline: 1.1265x; 1.1265x over previous
//
#include <hip/hip_runtime.h>

#define IN_DIM 2048
#define OUT_DIM 2048
#define EPS 1e-8f

#define BK 128                 // i8 bytes per K-tile
#define NKT (IN_DIM / BK)      // 16 K-tiles
#define HALF 16384             // half-tile: 256 rows x 64 B (granule-major)
// LDS map (131072 B): A ks0 @ 0,16K | A ks1 @ 32K,48K | B ks0 @ 64K,80K | B ks1 @ 96K,112K

using int32x4 = __attribute__((ext_vector_type(4))) int;

// ---------------- Kernel 1: sum of |W| ----------------
__global__ __launch_bounds__(256) void absum_kernel(const float* __restrict__ w,
                                                    double* __restrict__ sum, int n4) {
    int tid = blockIdx.x * blockDim.x + threadIdx.x;
    int stride = gridDim.x * blockDim.x;
    float s = 0.f;
    for (int i = tid; i < n4; i += stride) {
        float4 v = ((const float4*)w)[i];
        s += fabsf(v.x) + fabsf(v.y) + fabsf(v.z) + fabsf(v.w);
    }
    for (int off = 32; off; off >>= 1) s += __shfl_down(s, off);
    __shared__ float wsum[4];
    int lane = threadIdx.x & 63, wave = threadIdx.x >> 6;
    if (lane == 0) wsum[wave] = s;
    __syncthreads();
    if (threadIdx.x == 0) {
        double t = (double)wsum[0] + (double)wsum[1] + (double)wsum[2] + (double)wsum[3];
        atomicAdd(sum, t);
    }
}

// ---------------- Kernel 2: quantize W to ternary int8 ----------------
__global__ __launch_bounds__(256) void quantw_kernel(const float* __restrict__ w,
                                                     const double* __restrict__ sumptr,
                                                     signed char* __restrict__ wq,
                                                     float* __restrict__ alpha_out, int n4) {
    float alpha = fmaxf((float)(*sumptr * (1.0 / (double)(IN_DIM * OUT_DIM))), EPS);
    int i = blockIdx.x * blockDim.x + threadIdx.x;
    if (i == 0) *alpha_out = alpha;
    if (i >= n4) return;
    float4 v = ((const float4*)w)[i];
    char4 q;
    q.x = (signed char)fminf(fmaxf(rintf(v.x / alpha), -1.f), 1.f);
    q.y = (signed char)fminf(fmaxf(rintf(v.y / alpha), -1.f), 1.f);
    q.z = (signed char)fminf(fmaxf(rintf(v.z / alpha), -1.f), 1.f);
    q.w = (signed char)fminf(fmaxf(rintf(v.w / alpha), -1.f), 1.f);
    ((char4*)wq)[i] = q;
}

// ---------------- Kernel 3: per-token beta + quantize x ----------------
__global__ __launch_bounds__(256) void quantx_kernel(const float* __restrict__ x,
                                                     signed char* __restrict__ xq,
                                                     float* __restrict__ beta_arr,
                                                     int tokens) {
    const int tid = threadIdx.x;
    const int lane = tid & 63, wave = tid >> 6;
    __shared__ float wmax[4];
    for (int t = blockIdx.x; t < tokens; t += gridDim.x) {
        const float4* row = (const float4*)(x + (size_t)t * IN_DIM);
        float4 v0 = row[tid];
        float4 v1 = row[tid + 256];
        float m = fmaxf(fmaxf(fmaxf(fabsf(v0.x), fabsf(v0.y)), fmaxf(fabsf(v0.z), fabsf(v0.w))),
                        fmaxf(fmaxf(fabsf(v1.x), fabsf(v1.y)), fmaxf(fabsf(v1.z), fabsf(v1.w))));
        for (int off = 32; off; off >>= 1) m = fmaxf(m, __shfl_xor(m, off));
        if (lane == 0) wmax[wave] = m;
        __syncthreads();
        m = fmaxf(fmaxf(wmax[0], wmax[1]), fmaxf(wmax[2], wmax[3]));
        float beta = fmaxf(m * (1.f / 127.f), EPS);
        if (tid == 0) beta_arr[t] = beta;
        char4 q0, q1;
        q0.x = (signed char)fminf(fmaxf(rintf(v0.x / beta), -127.f), 127.f);
        q0.y = (signed char)fminf(fmaxf(rintf(v0.y / beta), -127.f), 127.f);
        q0.z = (signed char)fminf(fmaxf(rintf(v0.z / beta), -127.f), 127.f);
        q0.w = (signed char)fminf(fmaxf(rintf(v0.w / beta), -127.f), 127.f);
        q1.x = (signed char)fminf(fmaxf(rintf(v1.x / beta), -127.f), 127.f);
        q1.y = (signed char)fminf(fmaxf(rintf(v1.y / beta), -127.f), 127.f);
        q1.z = (signed char)fminf(fmaxf(rintf(v1.z / beta), -127.f), 127.f);
        q1.w = (signed char)fminf(fmaxf(rintf(v1.w / beta), -127.f), 127.f);
        char4* orow = (char4*)(xq + (size_t)t * IN_DIM);
        orow[tid] = q0;
        orow[tid + 256] = q1;
        __syncthreads();
    }
}

// ---------------- GEMM helpers ----------------
__device__ __forceinline__ void gll(const signed char* g, signed char* l) {
    __builtin_amdgcn_global_load_lds((const __attribute__((address_space(1))) void*)g,
        (__attribute__((address_space(3))) void*)l, 16, 0, 0);
}

// m201-style phase skeleton: pre-MFMA gate pins the read->MFMA split at the barrier
#define PRE_MFMA()                                              \
    __builtin_amdgcn_s_barrier();                               \
    asm volatile("s_waitcnt lgkmcnt(0)" ::: "memory");          \
    __builtin_amdgcn_sched_barrier(0);

#define MFMA16(BASE, AF)                                                                       \
    __builtin_amdgcn_s_setprio(1);                                                             \
    _Pragma("unroll")                                                                          \
    for (int m_ = 0; m_ < 4; ++m_)                                                             \
        _Pragma("unroll")                                                                      \
        for (int n_ = 0; n_ < 4; ++n_)                                                         \
            acc[(BASE) + m_][n_] = __builtin_amdgcn_mfma_i32_16x16x64_i8(                      \
                AF[m_], bf[n_], acc[(BASE) + m_][n_], 0, 0, 0);                                \
    __builtin_amdgcn_s_setprio(0);

// One K-tile as FOUR barrier-pair phases (m201 8-phase template, i8 port):
//   P1: read af(ks0,lo)+bf(ks0) [8] | gll Ah0(T+1) | BAR lgkm0 | 16 MFMA acc[0..3] | BAR
//   P2: read af(ks0,hi)         [4] | gll Bh0(T+1) | BAR lgkm0 | 16 MFMA acc[4..7] | vmcnt(4) BAR
//   P3: read af(ks1,lo)+bf(ks1) [8] | gll Ah1(T+1) | BAR lgkm0 | 16 MFMA acc[0..3] | BAR
//   P4: read af(ks1,hi)         [4] | gll Bh1(T+1) | BAR lgkm0 | 16 MFMA acc[4..7] | vmcnt(4) BAR
// vmcnt(4) at P2-end gates Ah1/Bh1(T) (read in P3); at P4-end gates Ah0/Bh0(T+1)
// (read in P1 of T+1). Never vmcnt(0) in the main loop; tail drains with vmcnt(0).
template<bool STG, bool TAIL>
__device__ __forceinline__ void ktile(int T, signed char* lds, int32x4 (&acc)[8][4],
                                      int aoff, int boff, int f0, int f1,
                                      const signed char* a0, const signed char* a1,
                                      const signed char* b0, const signed char* b1) {
    const int s = (T & 1) * HALF;
    const int d = ((T + 1) & 1) * HALF;
    const size_t ko = (size_t)(T + 1) * BK;
    int32x4 af[4], bf[4];

    // ---- P1 ----
#pragma unroll
    for (int m = 0; m < 4; ++m) af[m] = *(const int32x4*)(lds + s + aoff + m * 1024);
#pragma unroll
    for (int n = 0; n < 4; ++n) bf[n] = *(const int32x4*)(lds + 65536 + s + boff + n * 1024);
    if constexpr (STG) { gll(a0 + ko, lds + d + f0); gll(a1 + ko, lds + d + f1); }
    PRE_MFMA()
    MFMA16(0, af)
    __builtin_amdgcn_s_barrier();

    // ---- P2 ----
#pragma unroll
    for (int m = 0; m < 4; ++m) af[m] = *(const int32x4*)(lds + s + aoff + 4096 + m * 1024);
    if constexpr (STG) { gll(b0 + ko, lds + 65536 + d + f0); gll(b1 + ko, lds + 65536 + d + f1); }
    PRE_MFMA()
    MFMA16(4, af)
    if constexpr (TAIL) asm volatile("s_waitcnt vmcnt(0)" ::: "memory");
    else                asm volatile("s_waitcnt vmcnt(4)" ::: "memory");
    __builtin_amdgcn_s_barrier();

    // ---- P3 ----
#pragma unroll
    for (int m = 0; m < 4; ++m) af[m] = *(const int32x4*)(lds + 32768 + s + aoff + m * 1024);
#pragma unroll
    for (int n = 0; n < 4; ++n) bf[n] = *(const int32x4*)(lds + 98304 + s + boff + n * 1024);
    if constexpr (STG) { gll(a0 + ko + 64, lds + 32768 + d + f0); gll(a1 + ko + 64, lds + 32768 + d + f1); }
    PRE_MFMA()
    MFMA16(0, af)
    __builtin_amdgcn_s_barrier();

    // ---- P4 ----
#pragma unroll
    for (int m = 0; m < 4; ++m) af[m] = *(const int32x4*)(lds + 32768 + s + aoff + 4096 + m * 1024);
    if constexpr (STG) { gll(b0 + ko + 64, lds + 98304 + d + f0); gll(b1 + ko + 64, lds + 98304 + d + f1); }
    PRE_MFMA()
    MFMA16(4, af)
    if constexpr (!TAIL) {
        asm volatile("s_waitcnt vmcnt(4)" ::: "memory");
        __builtin_amdgcn_s_barrier();
    }
}

// ---------------- Kernel 4: int8 MFMA GEMM, 256x256 tile ----------------
// 512 threads = 8 waves (2M x 4N); wave-tile 128x64; acc[8][4] (128 VGPR).
// Granule-major half-tiles (0 bank conflicts), dbuf-2 slots, counted vmcnt(4),
// 4 barrier-pair phases per K-tile (m201 schedule).
__global__ __launch_bounds__(512, 2) void gemm_kernel(const signed char* __restrict__ xq,
                                                      const signed char* __restrict__ wq,
                                                      const float* __restrict__ beta,
                                                      const float* __restrict__ alpha_p,
                                                      float* __restrict__ out) {
    extern __shared__ signed char lds[];   // 131072
    const int tid = threadIdx.x;
    const int lane = tid & 63;
    const int wave = tid >> 6;
    const int wm = wave >> 2;              // 0..1
    const int wn = wave & 3;               // 0..3
    const int row0 = blockIdx.x * 256;
    const int col0 = blockIdx.y * 256;

    // staging: 2 x 16B chunks per half-tile per thread (granule-major:
    // addr = g*1024 + kg*256 + r*16; row = g*16+r, kg = 16B k-group)
    const int f0 = tid * 16;
    const int f1 = f0 + 8192;
    const int g0 = f0 >> 10, kg0 = (f0 >> 8) & 3, r0 = (f0 >> 4) & 15;
    const int g1 = f1 >> 10, kg1 = (f1 >> 8) & 3, r1 = (f1 >> 4) & 15;
    const signed char* a0 = xq + (size_t)(row0 + g0 * 16 + r0) * IN_DIM + kg0 * 16;
    const signed char* a1 = xq + (size_t)(row0 + g1 * 16 + r1) * IN_DIM + kg1 * 16;
    const signed char* b0 = wq + (size_t)(col0 + g0 * 16 + r0) * IN_DIM + kg0 * 16;
    const signed char* b1 = wq + (size_t)(col0 + g1 * 16 + r1) * IN_DIM + kg1 * 16;

    const int kr = (lane >> 4) * 256 + (lane & 15) * 16;
    const int aoff = wm * 8192 + kr;       // + mh*4096 + m*1024
    const int boff = wn * 4096 + kr;       // + n*1024

    int32x4 acc[8][4] = {};

    // prologue: tile 0's four half-tiles into slot 0 (consumption order)
    gll(a0, lds + f0);              gll(a1, lds + f1);               // Ah0
    gll(b0, lds + 65536 + f0);      gll(b1, lds + 65536 + f1);       // Bh0
    gll(a0 + 64, lds + 32768 + f0); gll(a1 + 64, lds + 32768 + f1);  // Ah1
    gll(b0 + 64, lds + 98304 + f0); gll(b1 + 64, lds + 98304 + f1);  // Bh1
    asm volatile("s_waitcnt vmcnt(4)" ::: "memory");                 // Ah0,Bh0 landed
    __builtin_amdgcn_s_barrier();

    for (int T = 0; T < NKT - 1; ++T)
        ktile<true, false>(T, lds, acc, aoff, boff, f0, f1, a0, a1, b0, b1);
    ktile<false, true>(NKT - 1, lds, acc, aoff, boff, f0, f1, a0, a1, b0, b1);

    // epilogue: dequant + store (C layout: col=lane&15, row=(lane>>4)*4+reg)
    const float alpha = *alpha_p;
#pragma unroll
    for (int mi = 0; mi < 8; ++mi) {
        int rbase = row0 + wm * 128 + mi * 16 + ((lane >> 4) << 2);
#pragma unroll
        for (int r = 0; r < 4; ++r) {
            int row = rbase + r;
            float scale = alpha * beta[row];
#pragma unroll
            for (int n = 0; n < 4; ++n) {
                int col = col0 + wn * 64 + n * 16 + (lane & 15);
                out[(size_t)row * OUT_DIM + col] = (float)acc[mi][n][r] * scale;
            }
        }
    }
}

extern "C" void kernel_launch(void* const* d_in, const int* in_sizes, int n_in,
                              void* d_out, int out_size, void* d_ws, size_t ws_size,
                              hipStream_t stream) {
    const float* x = (const float*)d_in[0];
    const float* w = (const float*)d_in[1];
    float* out = (float*)d_out;

    const int tokens = in_sizes[0] / IN_DIM;          // 16384
    const int n_w = in_sizes[1];                      // 4194304
    const int n_w4 = n_w / 4;

    char* ws = (char*)d_ws;
    double* d_sum = (double*)ws;                      // 8 B
    float* d_alpha = (float*)(ws + 8);                // 4 B
    float* d_beta = (float*)(ws + 256);               // tokens * 4 B
    signed char* d_wq = (signed char*)(ws + 256 + 65536);
    signed char* d_xq = d_wq + (size_t)n_w;

    hipMemsetAsync(d_ws, 0, 16, stream);

    absum_kernel<<<1024, 256, 0, stream>>>(w, d_sum, n_w4);
    quantw_kernel<<<(n_w4 + 255) / 256, 256, 0, stream>>>(w, d_sum, d_wq, d_alpha, n_w4);
    quantx_kernel<<<2048, 256, 0, stream>>>(x, d_xq, d_beta, tokens);

    hipFuncSetAttribute((const void*)gemm_kernel,
                        hipFuncAttributeMaxDynamicSharedMemorySize, 131072);

    dim3 grid(16384 / 256, OUT_DIM / 256);            // (64, 8)
    gemm_kernel<<<grid, 512, 131072, stream>>>(d_xq, d_wq, d_beta, d_alpha, out);
}